// Round 2
// baseline (275.940 us; speedup 1.0000x reference)
//
#include <hip/hip_runtime.h>

namespace {

constexpr int   kT     = 512;
constexpr int   kC     = 512;
constexpr int   kL     = 128;
constexpr int   kBlank = kC - 1;     // 511
constexpr int   kR     = 8;          // row ring depth (rows)
constexpr float kNeg   = -1e30f;
constexpr float kEps   = 1e-7f;

typedef float __attribute__((address_space(1))) f32g;
typedef float __attribute__((address_space(3))) f32l;

__device__ __forceinline__ void load_row_half(const float* g, float* lds) {
    // 16 B/lane, wave-uniform LDS base + lane*16 (HW rule), per-lane global addr.
    __builtin_amdgcn_global_load_lds((const f32g*)g, (f32l*)lds, 16, 0, 0);
}

__device__ __forceinline__ float rlane(float x, int l) {
    return __int_as_float(__builtin_amdgcn_readlane(__float_as_int(x), l));
}

__global__ __launch_bounds__(64, 1) void ctc_fwd_kernel(
        const int* __restrict__ labels,
        const float* __restrict__ y_pred,
        float* __restrict__ out) {
    __shared__ __align__(16) float rowbuf[kR][kC];   // 16 KiB ring of prob rows

    const int lane = (int)threadIdx.x;               // 64-thread block = 1 wave
    const int b    = (int)blockIdx.x;
    const float* yp = y_pred + (size_t)b * kT * kC;

    // ---- per-lane label constants: state s = lane + 64k ----
    int  ecls[4];
    bool skp[4];
    const bool odd = (lane & 1) != 0;
#pragma unroll
    for (int k = 0; k < 4; ++k) {
        const int s  = lane + 64 * k;
        const int i1 = (s >= 1) ? ((s - 1) >> 1) : 0;
        int lab1 = kBlank, lab2 = -1;
        if (odd) {
            lab1 = labels[b * kL + i1];
            if (s >= 3) lab2 = labels[b * kL + i1 - 1];
        }
        ecls[k] = odd ? lab1 : kBlank;
        skp[k]  = odd && (s >= 3) && (lab1 != lab2);
    }

    // Drain label loads so in-loop vmcnt counts ONLY row loads (exact).
    asm volatile("s_waitcnt vmcnt(0)" ::: "memory");

    // ---- prologue: fill ring with rows 0..7 (2 loads per row) ----
#pragma unroll
    for (int r = 0; r < kR; ++r) {
        load_row_half(yp + r * kC + lane * 4,       &rowbuf[r][0]);
        load_row_half(yp + r * kC + 256 + lane * 4, &rowbuf[r][256]);
    }

    asm volatile("s_waitcnt vmcnt(14)" ::: "memory");   // row 0 ready
    float a[4], a256 = kNeg;
    {
        const float r0 = rowbuf[0][ecls[0]];  // lane0: blank, lane1: labels[0]
        a[0] = (lane < 2) ? __logf(r0 + kEps) : kNeg;
        a[1] = kNeg; a[2] = kNeg; a[3] = kNeg;
    }

    asm volatile("s_waitcnt vmcnt(12)" ::: "memory");   // row 1 ready
    float lp[4];
#pragma unroll
    for (int k = 0; k < 4; ++k) lp[k] = __logf(rowbuf[1][ecls[k]] + kEps);

    const int addr1 = (lane - 1) << 2;   // bpermute byte addrs (lane<delta fixed by select)
    const int addr2 = (lane - 2) << 2;

    // ---- forward recursion, barrier-free, one wave ----
    for (int t = 1; t < kT; ++t) {
        // prefetch row t+7 (clamped tail) into slot (t+7)&7
        {
            int r = t + 7; if (r > kT - 1) r = kT - 1;
            const int sl = (t + 7) & (kR - 1);
            load_row_half(yp + (size_t)r * kC + lane * 4,       &rowbuf[sl][0]);
            load_row_half(yp + (size_t)r * kC + 256 + lane * 4, &rowbuf[sl][256]);
        }
        // keep 6 rows (12 loads) in flight; guarantees row t+1 is resident
        asm volatile("s_waitcnt vmcnt(12)" ::: "memory");

        // gather raw probs for row t+1 (off the critical α path)
        const int sln = (t + 1) & (kR - 1);
        float raw[4];
#pragma unroll
        for (int k = 0; k < 4; ++k) raw[k] = rowbuf[sln][ecls[k]];

        // α update for states 0..255 using lp (row t)
        float an[4];
#pragma unroll
        for (int k = 0; k < 4; ++k) {
            const float s1 = __int_as_float(
                __builtin_amdgcn_ds_bpermute(addr1, __float_as_int(a[k])));
            const float s2 = __int_as_float(
                __builtin_amdgcn_ds_bpermute(addr2, __float_as_int(a[k])));
            float am1, am2;
            if (k == 0) {
                am1 = (lane == 0) ? kNeg : s1;
                am2 = (lane <= 1) ? kNeg : s2;
            } else {
                const float e63 = rlane(a[k - 1], 63);
                const float e62 = rlane(a[k - 1], 62);
                am1 = (lane == 0) ? e63 : s1;
                am2 = (lane == 0) ? e62 : ((lane == 1) ? e63 : s2);
            }
            const float a3v = skp[k] ? am2 : kNeg;
            const float m   = fmaxf(fmaxf(a[k], am1), a3v);
            const float sum = __expf(a[k] - m) + __expf(am1 - m) + __expf(a3v - m);
            an[k] = m + __logf(sum) + lp[k];
        }
        // state 256 (uniform scalar update; lp[0] lane0 is the blank class)
        {
            const float a255 = rlane(a[3], 63);
            const float lpb  = rlane(lp[0], 0);
            const float m    = fmaxf(a256, a255);
            a256 = m + __logf(__expf(a256 - m) + __expf(a255 - m)) + lpb;
        }
#pragma unroll
        for (int k = 0; k < 4; ++k) { a[k] = an[k]; lp[k] = __logf(raw[k] + kEps); }
    }

    // ---- loss = -logaddexp(alpha[256], alpha[255]) ----
    {
        const float a255 = rlane(a[3], 63);
        const float m    = fmaxf(a256, a255);
        const float loss = -(m + __logf(__expf(a256 - m) + __expf(a255 - m)));
        if (lane == 0) out[b] = loss;
    }
}

} // namespace

extern "C" void kernel_launch(void* const* d_in, const int* in_sizes, int n_in,
                              void* d_out, int out_size, void* d_ws, size_t ws_size,
                              hipStream_t stream) {
    const int*   labels = (const int*)d_in[0];   // y_true [256,128] int32
    const float* y_pred = (const float*)d_in[1]; // y_pred [256,512,512] f32
    float*       out    = (float*)d_out;         // loss [256,1] f32
    (void)in_sizes; (void)n_in; (void)d_ws; (void)ws_size;
    hipLaunchKernelGGL(ctc_fwd_kernel, dim3(out_size), dim3(64), 0, stream,
                       labels, y_pred, out);
}

// Round 3
// 237.670 us; speedup vs baseline: 1.1610x; 1.1610x over previous
//
#include <hip/hip_runtime.h>

namespace {

constexpr int   kT     = 512;
constexpr int   kC     = 512;
constexpr int   kL     = 128;
constexpr int   kBlank = kC - 1;     // 511
constexpr int   kPF    = 8;          // register prefetch depth (rows)
constexpr float kNeg   = -1e30f;
constexpr float kEps   = 1e-7f;
constexpr float kLn2   = 0.6931471805599453f;

__device__ __forceinline__ float rlane(float x, int l) {
    return __int_as_float(__builtin_amdgcn_readlane(__float_as_int(x), l));
}
__device__ __forceinline__ float bperm(int addr, float x) {
    return __int_as_float(__builtin_amdgcn_ds_bpermute(addr, __float_as_int(x)));
}

__global__ __launch_bounds__(64, 1) void ctc_fwd_kernel(
        const int* __restrict__ labels,
        const float* __restrict__ y_pred,
        float* __restrict__ out) {
    const int lane = (int)threadIdx.x;               // 1 wave per block
    const int b    = (int)blockIdx.x;
    const float* yp = y_pred + (size_t)b * kT * kC;

    // ---- per-lane label constants: state s = lane + 64k ----
    int  ecls[4];
    bool skp[4];
    const bool odd = (lane & 1) != 0;
#pragma unroll
    for (int k = 0; k < 4; ++k) {
        const int s  = lane + 64 * k;
        const int i1 = (s >= 1) ? ((s - 1) >> 1) : 0;
        int lab1 = kBlank, lab2 = -1;
        if (odd) {
            lab1 = labels[b * kL + i1];
            if (s >= 3) lab2 = labels[b * kL + i1 - 1];
        }
        ecls[k] = odd ? lab1 : kBlank;
        skp[k]  = odd && (s >= 3) && (lab1 != lab2);
    }

    // ---- register ring of gathered probs; slot = row & 7, statically indexed ----
    float rawbuf[kPF][4];

    // row 0 (for alpha init)
    const float raw0 = yp[ecls[0]];

    // prologue: issue gathers for rows 1..8 into slots 1..7,0
#pragma unroll
    for (int r = 1; r <= kPF; ++r) {
        const float* rowp = yp + r * kC;
#pragma unroll
        for (int k = 0; k < 4; ++k) rawbuf[r & (kPF - 1)][k] = rowp[ecls[k]];
    }

    // ---- t = 0 init (log2 domain) ----
    float a[4], a256 = kNeg;
    a[0] = (lane < 2) ? __log2f(raw0 + kEps) : kNeg;
    a[1] = kNeg; a[2] = kNeg; a[3] = kNeg;

    const int addr1 = (lane - 1) << 2;   // bpermute byte addrs
    const int addr2 = (lane - 2) << 2;

    // one time step; slot is a compile-time constant after unrolling
#define CTC_STEP(T_, SLOT_, PREFETCH_)                                         \
    {                                                                          \
        float lp2[4];                                                          \
        _Pragma("unroll")                                                      \
        for (int k = 0; k < 4; ++k)                                            \
            lp2[k] = __log2f(rawbuf[SLOT_][k] + kEps);                         \
        if (PREFETCH_) {                                                       \
            const int rr = ((T_) + kPF < kT) ? (T_) + kPF : kT - 1;            \
            const float* rowp = yp + rr * kC;                                  \
            _Pragma("unroll")                                                  \
            for (int k = 0; k < 4; ++k) rawbuf[SLOT_][k] = rowp[ecls[k]];      \
        }                                                                      \
        float an[4];                                                           \
        _Pragma("unroll")                                                      \
        for (int k = 0; k < 4; ++k) {                                          \
            const float s1 = bperm(addr1, a[k]);                               \
            const float s2 = bperm(addr2, a[k]);                               \
            float am1, am2;                                                    \
            if (k == 0) {                                                      \
                am1 = (lane == 0) ? kNeg : s1;                                 \
                am2 = (lane <= 1) ? kNeg : s2;                                 \
            } else {                                                           \
                const float e63 = rlane(a[k - 1], 63);                         \
                const float e62 = rlane(a[k - 1], 62);                         \
                am1 = (lane == 0) ? e63 : s1;                                  \
                am2 = (lane == 0) ? e62 : ((lane == 1) ? e63 : s2);            \
            }                                                                  \
            const float a3v = skp[k] ? am2 : kNeg;                             \
            const float m   = fmaxf(fmaxf(a[k], am1), a3v);                    \
            const float sum = exp2f(a[k] - m) + exp2f(am1 - m)                 \
                            + exp2f(a3v - m);                                  \
            an[k] = m + __log2f(sum) + lp2[k];                                 \
        }                                                                      \
        {                                                                      \
            const float a255 = rlane(a[3], 63);                                \
            const float lpb  = rlane(lp2[0], 0);                               \
            const float m    = fmaxf(a256, a255);                              \
            a256 = m + __log2f(exp2f(a256 - m) + exp2f(a255 - m)) + lpb;       \
        }                                                                      \
        _Pragma("unroll")                                                      \
        for (int k = 0; k < 4; ++k) a[k] = an[k];                              \
    }

    // ---- main loop: t = 1..504, unrolled x8 (tb ≡ 1 mod 8 → slot = (1+u)&7) ----
    for (int tb = 1; tb + kPF <= kT; tb += kPF) {
#pragma unroll
        for (int u = 0; u < kPF; ++u) {
            CTC_STEP(tb + u, ((1 + u) & (kPF - 1)), 1);
        }
    }
    // ---- tail: t = 505..511, rows already prefetched, no new issues ----
#pragma unroll
    for (int u = 0; u < kPF - 1; ++u) {
        CTC_STEP(505 + u, ((1 + u) & (kPF - 1)), 0);
    }
#undef CTC_STEP

    // ---- loss = -ln2 * logaddexp2(alpha[256], alpha[255]) ----
    {
        const float a255 = rlane(a[3], 63);
        const float m    = fmaxf(a256, a255);
        const float loss = -kLn2 * (m + __log2f(exp2f(a256 - m) + exp2f(a255 - m)));
        if (lane == 0) out[b] = loss;
    }
}

} // namespace

extern "C" void kernel_launch(void* const* d_in, const int* in_sizes, int n_in,
                              void* d_out, int out_size, void* d_ws, size_t ws_size,
                              hipStream_t stream) {
    const int*   labels = (const int*)d_in[0];   // y_true [256,128] int32
    const float* y_pred = (const float*)d_in[1]; // y_pred [256,512,512] f32
    float*       out    = (float*)d_out;         // loss [256,1] f32
    (void)in_sizes; (void)n_in; (void)d_ws; (void)ws_size;
    hipLaunchKernelGGL(ctc_fwd_kernel, dim3(out_size), dim3(64), 0, stream,
                       labels, y_pred, out);
}